// Round 10
// baseline (179.806 us; speedup 1.0000x reference)
//
#include <hip/hip_runtime.h>

typedef __bf16 bf16_t;
typedef unsigned short u16;
typedef __attribute__((ext_vector_type(8))) __bf16 bf16x8;
typedef __attribute__((ext_vector_type(4))) float f32x4;
typedef __attribute__((ext_vector_type(4))) u16 u16x4;
typedef __attribute__((ext_vector_type(8))) u16 u16x8;

#define SS 2048

__device__ __forceinline__ u16 f2b(float f) {
    return __builtin_bit_cast(u16, (__bf16)f);
}

// exp2 in ONE VALU op (v_exp_f32).
__device__ __forceinline__ float fexp2(float x) {
#if __has_builtin(__builtin_amdgcn_exp2f)
    return __builtin_amdgcn_exp2f(x);
#else
    float r;
    asm("v_exp_f32 %0, %1" : "=v"(r) : "v"(x));
    return r;
#endif
}

__device__ __forceinline__ void async_copy16(const u16* g, u16* l) {
    __builtin_amdgcn_global_load_lds(
        (__attribute__((address_space(1))) void*)(u16*)g,
        (__attribute__((address_space(3))) void*)l, 16, 0, 0);
}

__device__ __forceinline__ bf16x8 ldfrag(const u16* p) {
    return __builtin_bit_cast(bf16x8, *(const u16x8*)p);
}

// ---------------- cast x: f32 -> bf16 ----------------
__global__ __launch_bounds__(256)
void cast_x_kernel(const float* __restrict__ x, u16* __restrict__ xb) {
    size_t i = ((size_t)blockIdx.x * 256 + threadIdx.x) * 8;
    float4 a = *(const float4*)(x + i);
    float4 b = *(const float4*)(x + i + 4);
    u16x8 o;
    o[0] = f2b(a.x); o[1] = f2b(a.y); o[2] = f2b(a.z); o[3] = f2b(a.w);
    o[4] = f2b(b.x); o[5] = f2b(b.y); o[6] = f2b(b.z); o[7] = f2b(b.w);
    *(u16x8*)(xb + i) = o;
}

// ------- fused transpose+cast of all 3 weights: src [1024][N] f32 -> dst [N][1024] bf16 -------
// z=0: Wq (scale = 0.125*log2e folded for exp2-domain softmax), z=1: Wkv, z=2: Wo
__global__ __launch_bounds__(256)
void transpose_all(const float* __restrict__ Wq, const float* __restrict__ Wkv,
                   const float* __restrict__ Wo, u16* __restrict__ WcatT,
                   u16* __restrict__ WoT) {
    const int z = blockIdx.z;
    if (z != 1 && blockIdx.y >= 16) return;
    const float* src; u16* dst; int N; float scale;
    if (z == 0)      { src = Wq;  dst = WcatT;               N = 1024; scale = 0.125f * 1.44269504089f; }
    else if (z == 1) { src = Wkv; dst = WcatT + 1024 * 1024; N = 2048; scale = 1.0f; }
    else             { src = Wo;  dst = WoT;                 N = 1024; scale = 1.0f; }
    __shared__ __attribute__((aligned(16))) u16 tile[64][72];
    const int k0 = blockIdx.x * 64, n0 = blockIdx.y * 64;
    const int tid = threadIdx.x;
#pragma unroll
    for (int p = 0; p < 4; ++p) {
        int c = p * 256 + tid;
        int r = c >> 4, c4 = c & 15;
        float4 v = *(const float4*)(src + (size_t)(k0 + r) * N + n0 + c4 * 4);
        u16x4 o;
        o[0] = f2b(v.x * scale); o[1] = f2b(v.y * scale);
        o[2] = f2b(v.z * scale); o[3] = f2b(v.w * scale);
        *(u16x4*)&tile[r][c4 * 4] = o;
    }
    __syncthreads();
#pragma unroll
    for (int p = 0; p < 4; ++p) {
        int c = p * 256 + tid;
        int n = c >> 4, k4 = c & 15;
        u16x4 o;
#pragma unroll
        for (int i = 0; i < 4; ++i) o[i] = tile[k4 * 4 + i][n];
        *(u16x4*)(dst + (size_t)(n0 + n) * 1024 + k0 + k4 * 4) = o;
    }
}

// ------- QKV GEMM, 8-PHASE 256x256 DEEP PIPELINE (T2+T3+T4+T5) -------
// R10: port of the verified 256^2 8-phase template. 512 thr = 8 waves (2Mx4N),
// BK=64, LDS 128KB: As/Bs[2 buf][2 half][128 rows][64 k], buf = ktile&1.
// Per phase: {4-12 ds_read || stage 1 half-tile via global_load_lds} -> barrier
// -> 16 MFMA (setprio-wrapped) -> barrier. Counted vmcnt(4) at phases 3 and 7
// ONLY (never 0 mid-loop): prefetch loads stay in flight across barriers.
// Wait ledger (per wave, 2 loads/stage): prologue 6 stages (A0,B0<-t0; B1<-t1),
// vmcnt(4) leaves B1 in flight. Iter i: ph0,1 stage A(buf1)<-t(2i+1) [needed
// THIS iter ph4-7, landed by ph3's vmcnt(4)]; ph2-5 stage B,A(buf0)<-t(2i+2);
// ph6,7 B(buf1)<-t(2i+3). ph3 wait retires {B1 prev, A1 this}=8; ph7 wait
// retires {B0,A0 next-tile}=8, leaves 4. Slot overwrites are barrier-separated
// from their last reads (B(buf0) last read ph0, overwritten ph2; A(buf0) read
// ph0-3, overwritten ph4; B(buf1) read ph4, overwritten ph6; A(buf1) read
// ph4-7, overwritten next-iter ph0). Last iter: ph2-7 stage nothing, ph3 wait
// = vmcnt(0) (no new loads to push the old ones out).
// T2 st_16x32 swizzle (essential at BK=64: linear rows = 128B stride = all
// lanes same banks): u16 col ^= ((row>>2)&1)<<4, applied BOTH sides —
// inverse-swizzled GLOBAL source (runs stay 16B-contiguous since the XOR only
// flips bit 4 of an 8-aligned run) + swizzled ds_read col. On the read side
// (row>>2)&1 = (l15>>2)&1 (mf*16 contributes 0) -> lane-constant cq.
// R7 sigma^-1 V-epilogue kept (2048 % 256 == 0 -> V blocks uniform).
__global__ __launch_bounds__(512, 2)
void gemm_qkv8(const u16* __restrict__ A, const u16* __restrict__ BT,
               u16* __restrict__ C, u16* __restrict__ VTg) {
    constexpr int K = 1024;
    constexpr int NITER = 8;   // 16 K-tiles, 2 per iteration
    __shared__ __attribute__((aligned(16))) u16 As[2][16384];
    __shared__ __attribute__((aligned(16))) u16 Bs[2][16384];
    const int tid = threadIdx.x;
    const int wave = tid >> 6, lane = tid & 63;
    const int l15 = lane & 15, quad = lane >> 4;
    const int wm = wave >> 2, wn = wave & 3;      // 2M x 4N wave grid
    // XCD-chunked decode: 192 blocks = 24/XCD exact
    const int wid = blockIdx.x;
    const int logical = (wid & 7) * 24 + (wid >> 3);
    const int ty = logical / 12, tx = logical - ty * 12;
    const int m0 = ty * 256, n0 = tx * 256;
    // staging coords: thread covers row r0h (+64 on 2nd issue), 8 u16 at c0
    const int r0h = tid >> 3, c0 = (tid & 7) * 8;
    const int csrc = c0 ^ (((r0h >> 2) & 1) << 4);   // inverse-swizzled source col
    // read-side swizzled k-col (lane-constant)
    const int cq = (quad * 8) ^ (((l15 >> 2) & 1) << 4);

    f32x4 acc[8][4];
    const f32x4 zero = {0.f, 0.f, 0.f, 0.f};
#pragma unroll
    for (int i = 0; i < 8; ++i)
#pragma unroll
        for (int j = 0; j < 4; ++j) acc[i][j] = zero;

    auto stageA = [&](int buf, int half, int kt) {
        const u16* s = A + (size_t)(m0 + half * 128 + r0h) * K + kt * 64 + csrc;
        u16* d = &As[buf][half * 8192 + tid * 8];
        async_copy16(s, d);
        async_copy16(s + (size_t)64 * K, d + 4096);
    };
    auto stageB = [&](int buf, int half, int kt) {
        const u16* s = BT + (size_t)(n0 + half * 128 + r0h) * K + kt * 64 + csrc;
        u16* d = &Bs[buf][half * 8192 + tid * 8];
        async_copy16(s, d);
        async_copy16(s + (size_t)64 * K, d + 4096);
    };
    auto dsA = [&](int buf, int mf, int ks) {
        return ldfrag(&As[buf][wm * 8192 + (mf * 16 + l15) * 64 + ks * 32 + cq]);
    };
    auto dsB = [&](int buf, int nf, int ks) {
        return ldfrag(&Bs[buf][(wn >> 1) * 8192 +
                               ((wn & 1) * 64 + nf * 16 + l15) * 64 + ks * 32 + cq]);
    };

    // prologue: A+B of tile0 into buf0, B of tile1 into buf1 (A of t1 = iter0 ph0,1)
    stageA(0, 0, 0); stageA(0, 1, 0);
    stageB(0, 0, 0); stageB(0, 1, 0);
    stageB(1, 0, 1); stageB(1, 1, 1);
    asm volatile("s_waitcnt vmcnt(4)" ::: "memory");  // t0 landed; B(t1) in flight
    __builtin_amdgcn_s_barrier();

    for (int i = 0; i < NITER; ++i) {
        const bool lastI = (i == NITER - 1);
        const int t1 = 2 * i + 1, t2 = 2 * i + 2, t3 = 2 * i + 3;
        bf16x8 bf[4][2], af[2][2];
#pragma unroll
        for (int ph = 0; ph < 8; ++ph) {
            const int kb = ph >> 2;      // read buf: 0 = tile 2i, 1 = tile 2i+1
            const int q = ph & 3;        // m-quadrant
            // ---- issue section: ds reads + 1 half-tile stage ----
            af[0][0] = dsA(kb, q * 2, 0);     af[0][1] = dsA(kb, q * 2, 1);
            af[1][0] = dsA(kb, q * 2 + 1, 0); af[1][1] = dsA(kb, q * 2 + 1, 1);
            if (q == 0) {
#pragma unroll
                for (int nf = 0; nf < 4; ++nf) {
                    bf[nf][0] = dsB(kb, nf, 0);
                    bf[nf][1] = dsB(kb, nf, 1);
                }
            }
            if (ph == 0)      stageA(1, 0, t1);   // always: needed this iter ph4-7
            else if (ph == 1) stageA(1, 1, t1);
            else if (!lastI) {
                if (ph == 2)      stageB(0, 0, t2);
                else if (ph == 3) stageB(0, 1, t2);
                else if (ph == 4) stageA(0, 0, t2);
                else if (ph == 5) stageA(0, 1, t2);
                else if (ph == 6) stageB(1, 0, t3);
                else              stageB(1, 1, t3);
            }
            __builtin_amdgcn_s_barrier();
            // ---- compute section (compiler inserts fine-grained lgkmcnt) ----
            __builtin_amdgcn_s_setprio(1);
#pragma unroll
            for (int mfq = 0; mfq < 2; ++mfq)
#pragma unroll
                for (int nf = 0; nf < 4; ++nf) {
                    acc[q * 2 + mfq][nf] = __builtin_amdgcn_mfma_f32_16x16x32_bf16(
                        af[mfq][0], bf[nf][0], acc[q * 2 + mfq][nf], 0, 0, 0);
                    acc[q * 2 + mfq][nf] = __builtin_amdgcn_mfma_f32_16x16x32_bf16(
                        af[mfq][1], bf[nf][1], acc[q * 2 + mfq][nf], 0, 0, 0);
                }
            __builtin_amdgcn_s_setprio(0);
            // ---- counted waits, BEFORE the closing barrier that gates the
            //      next phase's ds_reads ----
            if (ph == 3) {
                if (lastI) asm volatile("s_waitcnt vmcnt(0)" ::: "memory");
                else       asm volatile("s_waitcnt vmcnt(4)" ::: "memory");
            } else if (ph == 7 && !lastI) {
                asm volatile("s_waitcnt vmcnt(4)" ::: "memory");
            }
            __builtin_amdgcn_s_barrier();
        }
    }

    // ---- epilogue ----
    if (n0 >= 2048) {
        // V tile -> VT[bh][hd][s'] directly (sigma^-1), skip QKV C-write.
#pragma unroll
        for (int mf = 0; mf < 8; ++mf)
#pragma unroll
            for (int nf = 0; nf < 4; ++nf) {
                const int n_g = n0 + wn * 64 + nf * 16 + l15 - 2048;
                const int hd = n_g & 63, h = n_g >> 6;
                const int m_g = m0 + wm * 128 + mf * 16 + quad * 4;
                const int bb = m_g >> 11;
                const int s = m_g & 2047;
                const int sb = s & 63;
                const int col = (sb & 32) | ((sb & 12) << 1) | ((sb >> 2) & 4);
                u16x4 o;
#pragma unroll
                for (int r = 0; r < 4; ++r) o[r] = f2b(acc[mf][nf][r]);
                *(u16x4*)(VTg + ((size_t)(bb * 16 + h) * 64 + hd) * 2048
                          + (s & ~63) + col) = o;
            }
        return;
    }
#pragma unroll
    for (int mf = 0; mf < 8; ++mf)
#pragma unroll
        for (int nf = 0; nf < 4; ++nf) {
            const int n = n0 + wn * 64 + nf * 16 + l15;
            const int mb = m0 + wm * 128 + mf * 16 + quad * 4;
#pragma unroll
            for (int r = 0; r < 4; ++r)
                C[(size_t)(mb + r) * 3072 + n] = f2b(acc[mf][nf][r]);
        }
}

// ------- GEMM variant: 128x64 tile (for N=1024 out-proj). dbuf + XCD chunking. -------
__global__ __launch_bounds__(256, 2)
void gemm_bt64(const u16* __restrict__ A, const u16* __restrict__ BT,
               float* __restrict__ C, int M, int N, int K) {
    __shared__ __attribute__((aligned(16))) u16 As[2][128 * 32];
    __shared__ __attribute__((aligned(16))) u16 Bs[2][64 * 32];
    const int tid = threadIdx.x;
    const int wave = tid >> 6, lane = tid & 63;
    const int l15 = lane & 15, quad = lane >> 4;
    const int wid = blockIdx.x;
    const int per = (int)(gridDim.x >> 3);
    const int logical = (wid & 7) * per + (wid >> 3);
    const int nxt = N >> 6;
    const int ty = logical / nxt, tx = logical - ty * nxt;
    const int m0 = ty * 128, n0 = tx * 64;
    const int wm = (wave >> 1) * 64, wn = (wave & 1) * 32;
    const f32x4 zero = {0.f, 0.f, 0.f, 0.f};
    f32x4 acc[4][2];
#pragma unroll
    for (int i = 0; i < 4; ++i)
#pragma unroll
        for (int j = 0; j < 2; ++j) acc[i][j] = zero;
    const int r0 = tid >> 2, kc = (tid & 3) * 8;
    auto stage = [&](int bsel, int k0) {
        async_copy16(A + (size_t)(m0 + r0) * K + k0 + kc, As[bsel] + tid * 8);
        async_copy16(A + (size_t)(m0 + 64 + r0) * K + k0 + kc, As[bsel] + (256 + tid) * 8);
        async_copy16(BT + (size_t)(n0 + r0) * K + k0 + kc, Bs[bsel] + tid * 8);
    };
    stage(0, 0);
    __syncthreads();
    const int nk = K >> 5;
    for (int t = 0; t < nk; ++t) {
        if (t + 1 < nk) stage((t + 1) & 1, (t + 1) * 32);
        const u16* Ab = As[t & 1];
        const u16* Bb = Bs[t & 1];
        bf16x8 af[4], bf[2];
#pragma unroll
        for (int s = 0; s < 4; ++s)
            af[s] = ldfrag(Ab + (wm + s * 16 + l15) * 32 + quad * 8);
#pragma unroll
        for (int s = 0; s < 2; ++s)
            bf[s] = ldfrag(Bb + (wn + s * 16 + l15) * 32 + quad * 8);
#pragma unroll
        for (int mt = 0; mt < 4; ++mt)
#pragma unroll
            for (int nt = 0; nt < 2; ++nt)
                acc[mt][nt] = __builtin_amdgcn_mfma_f32_16x16x32_bf16(
                    af[mt], bf[nt], acc[mt][nt], 0, 0, 0);
        __syncthreads();
    }
#pragma unroll
    for (int mt = 0; mt < 4; ++mt)
#pragma unroll
        for (int nt = 0; nt < 2; ++nt) {
            const int n = n0 + wn + nt * 16 + l15;
#pragma unroll
            for (int r = 0; r < 4; ++r) {
                const int m = m0 + wm + mt * 16 + quad * 4 + r;
                C[(size_t)m * N + n] = acc[mt][nt][r];
            }
        }
}

// ------- flash attention, causal, fixed-shift softmax, P-in-registers. -------
// R6 winner, UNCHANGED: dual-tile, KVBLK=64, XCD-chunked pair-balanced grid.
__global__ __launch_bounds__(256, 2)
void attn_kernel(const u16* __restrict__ QKV, const u16* __restrict__ VTg,
                 u16* __restrict__ AO) {
    __shared__ __attribute__((aligned(16))) u16 Kt[2][2 * 64 * 32];
    __shared__ __attribute__((aligned(16))) u16 Vt[2][2 * 64 * 32];
    const int tid = threadIdx.x;
    const int wave = tid >> 6, lane = tid & 63;
    const int l15 = lane & 15, quad = lane >> 4;
    const int w16 = wave * 16;
    // XCD-chunked, pair-balanced decode (512 blocks, 64 per XCD)
    const int wid = blockIdx.x;
    const int g = wid >> 3;                 // 0..63 slot within this XCD
    const int jj = g & 15, hf = jj >> 1;
    const int xe0 = (jj & 1) ? 15 - hf : hf;   // 0,15,1,14,...
    const int xe = (g & 32) ? 15 - xe0 : xe0;  // mirrored upper half
    const int bh = (wid & 7) * 4 + (g >> 4);   // 4 bh per XCD
    const int b = bh >> 4, h = bh & 15;
    const int qbA = 31 - xe, qbB = xe;
    const int qA0 = qbA * 64, qB0 = qbB * 64;
    const size_t bS = (size_t)b * SS;
    const u16* vbase = VTg + (size_t)bh * 64 * 2048;
    const int rr = (tid >> 2) & 63, kc8 = (tid & 3) * 8;

    // stage kv block 0
    {
        const u16* ksrc = QKV + (bS + rr) * 3072 + 1024 + h * 64 + kc8;
        async_copy16(ksrc,      Kt[0] + tid * 8);
        async_copy16(ksrc + 32, Kt[0] + (256 + tid) * 8);
        const u16* vsrc = vbase + (size_t)rr * 2048 + kc8;
        async_copy16(vsrc,      Vt[0] + tid * 8);
        async_copy16(vsrc + 32, Vt[0] + (256 + tid) * 8);
    }
    // Q direct global->reg: wave's own 16 q-rows per tile
    bf16x8 qfA[2], qfB[2];
    {
        const u16* qA = QKV + (bS + qA0 + w16 + l15) * 3072 + h * 64 + quad * 8;
        qfA[0] = ldfrag(qA); qfA[1] = ldfrag(qA + 32);
        const u16* qB = QKV + (bS + qB0 + w16 + l15) * 3072 + h * 64 + quad * 8;
        qfB[0] = ldfrag(qB); qfB[1] = ldfrag(qB + 32);
    }
    float lA = 0.f, lB = 0.f;
    f32x4 OA[4], OB[4];
    const f32x4 zero = {0.f, 0.f, 0.f, 0.f};
#pragma unroll
    for (int nt = 0; nt < 4; ++nt) { OA[nt] = zero; OB[nt] = zero; }
    const f32x4 cinit = {-10.f, -10.f, -10.f, -10.f};  // folded softmax shift
    __syncthreads();  // kv block 0 staged

    for (int j = 0; j <= qbA; ++j) {
        if (j < qbA) {  // prefetch j+1; drained by end-of-iter barrier (full cover)
            const int kv1 = (j + 1) * 64;
            const int nb = (j + 1) & 1;
            const u16* ksrc = QKV + (bS + kv1 + rr) * 3072 + 1024 + h * 64 + kc8;
            async_copy16(ksrc,      Kt[nb] + tid * 8);
            async_copy16(ksrc + 32, Kt[nb] + (256 + tid) * 8);
            const u16* vsrc = vbase + (size_t)rr * 2048 + kv1 + kc8;
            async_copy16(vsrc,      Vt[nb] + tid * 8);
            async_copy16(vsrc + 32, Vt[nb] + (256 + tid) * 8);
        }
        const bool bAct = (j <= qbB);  // block-uniform
        const bool dA = (j == qbA), dB = (j == qbB);
        const u16* KB = Kt[j & 1];
        const u16* VB = Vt[j & 1];
        bf16x8 vf[4][2];
#pragma unroll
        for (int nt = 0; nt < 4; ++nt)
#pragma unroll
            for (int ks = 0; ks < 2; ++ks)
                vf[nt][ks] = ldfrag(VB + ks * 2048 + (nt * 16 + l15) * 32 + quad * 8);
        // S^T over all 4 kv-subtiles for this wave's q-rows; P stays in regs.
        u16x4 pcA[4], pcB[4];
#pragma unroll
        for (int c = 0; c < 4; ++c) {
            bf16x8 kf0 = ldfrag(KB + (c * 16 + l15) * 32 + quad * 8);
            bf16x8 kf1 = ldfrag(KB + 2048 + (c * 16 + l15) * 32 + quad * 8);
            f32x4 a = __builtin_amdgcn_mfma_f32_16x16x32_bf16(kf0, qfA[0], cinit, 0, 0, 0);
            f32x4 s = __builtin_amdgcn_mfma_f32_16x16x32_bf16(kf1, qfA[1], a, 0, 0, 0);
            if (dA) {  // mask iff local kv > local q
#pragma unroll
                for (int r = 0; r < 4; ++r)
                    if (c * 16 + quad * 4 + r > w16 + l15) s[r] = -1e30f;
            }
            u16x4 pk; float acc = 0.f;
#pragma unroll
            for (int r = 0; r < 4; ++r) {
                float pv = fexp2(s[r]);
                acc += pv;
                pk[r] = f2b(pv);
            }
            lA += acc; pcA[c] = pk;
            if (bAct) {
                f32x4 a2 = __builtin_amdgcn_mfma_f32_16x16x32_bf16(kf0, qfB[0], cinit, 0, 0, 0);
                f32x4 s2 = __builtin_amdgcn_mfma_f32_16x16x32_bf16(kf1, qfB[1], a2, 0, 0, 0);
                if (dB) {
#pragma unroll
                    for (int r = 0; r < 4; ++r)
                        if (c * 16 + quad * 4 + r > w16 + l15) s2[r] = -1e30f;
                }
                u16x4 pk2; float acc2 = 0.f;
#pragma unroll
                for (int r = 0; r < 4; ++r) {
                    float pv = fexp2(s2[r]);
                    acc2 += pv;
                    pk2[r] = f2b(pv);
                }
                lB += acc2; pcB[c] = pk2;
            }
        }
        // PV: A-frag = own registers in (c,r) order, matching sigma-permuted V.
        bf16x8 paA[2], paB[2];
#pragma unroll
        for (int ks = 0; ks < 2; ++ks) {
            u16x8 t;
#pragma unroll
            for (int i = 0; i < 4; ++i) { t[i] = pcA[2 * ks][i]; t[4 + i] = pcA[2 * ks + 1][i]; }
            paA[ks] = __builtin_bit_cast(bf16x8, t);
        }
#pragma unroll
        for (int nt = 0; nt < 4; ++nt) {
            OA[nt] = __builtin_amdgcn_mfma_f32_16x16x32_bf16(paA[0], vf[nt][0], OA[nt], 0, 0, 0);
            OA[nt] = __builtin_amdgcn_mfma_f32_16x16x32_bf16(paA[1], vf[nt][1], OA[nt], 0, 0, 0);
        }
        if (bAct) {
#pragma unroll
            for (int ks = 0; ks < 2; ++ks) {
                u16x8 t;
#pragma unroll
                for (int i = 0; i < 4; ++i) { t[i] = pcB[2 * ks][i]; t[4 + i] = pcB[2 * ks + 1][i]; }
                paB[ks] = __builtin_bit_cast(bf16x8, t);
            }
#pragma unroll
            for (int nt = 0; nt < 4; ++nt) {
                OB[nt] = __builtin_amdgcn_mfma_f32_16x16x32_bf16(paB[0], vf[nt][0], OB[nt], 0, 0, 0);
                OB[nt] = __builtin_amdgcn_mfma_f32_16x16x32_bf16(paB[1], vf[nt][1], OB[nt], 0, 0, 0);
            }
        }
        __syncthreads();  // reads done + prefetch j+1 landed
    }

    // epilogue: all-shuffle. l partial per lane; xor16+xor32 sums the quads.
    lA += __shfl_xor(lA, 16); lA += __shfl_xor(lA, 32);
    lB += __shfl_xor(lB, 16); lB += __shfl_xor(lB, 32);
#pragma unroll
    for (int r = 0; r < 4; ++r) {
        const int ql = quad * 4 + r;   // local q row of O (D layout: row=quad*4+r)
        float invA = 1.0f / __shfl(lA, ql);
        float invB = 1.0f / __shfl(lB, ql);
        size_t rowA = bS + (size_t)qA0 + w16 + ql;
        size_t rowB = bS + (size_t)qB0 + w16 + ql;
#pragma unroll
        for (int nt = 0; nt < 4; ++nt) {
            AO[rowA * 1024 + h * 64 + nt * 16 + l15] = f2b(OA[nt][r] * invA);
            AO[rowB * 1024 + h * 64 + nt * 16 + l15] = f2b(OB[nt][r] * invB);
        }
    }
}

extern "C" void kernel_launch(void* const* d_in, const int* in_sizes, int n_in,
                              void* d_out, int out_size, void* d_ws, size_t ws_size,
                              hipStream_t stream) {
    (void)in_sizes; (void)n_in; (void)out_size; (void)ws_size;
    const float* x   = (const float*)d_in[0];
    const float* Wq  = (const float*)d_in[1];
    const float* Wkv = (const float*)d_in[2];
    const float* Wo  = (const float*)d_in[3];
    float* out = (float*)d_out;
    char* ws = (char*)d_ws;
    u16* xb    = (u16*)(ws);                      // 8 MB   x bf16 [4096][1024]
    u16* WcatT = (u16*)(ws + (size_t)(8 << 20));  // 6 MB   [Wq*s | Wkv]^T  [3072][1024]
    u16* WoT   = (u16*)(ws + (size_t)(14 << 20)); // 2 MB   Wo^T [1024][1024]
    u16* QKV   = (u16*)(ws + (size_t)(16 << 20)); // 24 MB  [4096][3072] (V cols unused)
    u16* VTb   = (u16*)(ws + (size_t)(40 << 20)); // 8 MB   [32][64][2048] sigma-permuted
    u16* AO    = xb;                              // reuse: xb dead after QKV GEMM

    cast_x_kernel<<<2048, 256, 0, stream>>>(x, xb);
    transpose_all<<<dim3(16, 32, 3), 256, 0, stream>>>(Wq, Wkv, Wo, WcatT, WoT);
    gemm_qkv8<<<192, 512, 0, stream>>>(xb, WcatT, QKV, VTb);
    attn_kernel<<<512, 256, 0, stream>>>(QKV, VTb, AO);
    gemm_bt64<<<512, 256, 0, stream>>>(AO, WoT, out, 4096, 1024, 1024);
}

// Round 11
// 172.651 us; speedup vs baseline: 1.0414x; 1.0414x over previous
//
#include <hip/hip_runtime.h>

typedef __bf16 bf16_t;
typedef unsigned short u16;
typedef __attribute__((ext_vector_type(8))) __bf16 bf16x8;
typedef __attribute__((ext_vector_type(4))) float f32x4;
typedef __attribute__((ext_vector_type(4))) u16 u16x4;
typedef __attribute__((ext_vector_type(8))) u16 u16x8;

#define SS 2048

__device__ __forceinline__ u16 f2b(float f) {
    return __builtin_bit_cast(u16, (__bf16)f);
}

// exp2 in ONE VALU op (v_exp_f32).
__device__ __forceinline__ float fexp2(float x) {
#if __has_builtin(__builtin_amdgcn_exp2f)
    return __builtin_amdgcn_exp2f(x);
#else
    float r;
    asm("v_exp_f32 %0, %1" : "=v"(r) : "v"(x));
    return r;
#endif
}

__device__ __forceinline__ void async_copy16(const u16* g, u16* l) {
    __builtin_amdgcn_global_load_lds(
        (__attribute__((address_space(1))) void*)(u16*)g,
        (__attribute__((address_space(3))) void*)l, 16, 0, 0);
}

__device__ __forceinline__ bf16x8 ldfrag(const u16* p) {
    return __builtin_bit_cast(bf16x8, *(const u16x8*)p);
}

// ---------------- cast x: f32 -> bf16 ----------------
// Dedicated memory-bound kernel. R8 proved fusing this into the GEMM A-staging
// is net-negative (vmcnt+cvt+conflicted ds_write on the K-loop critical path).
__global__ __launch_bounds__(256)
void cast_x_kernel(const float* __restrict__ x, u16* __restrict__ xb) {
    size_t i = ((size_t)blockIdx.x * 256 + threadIdx.x) * 8;
    float4 a = *(const float4*)(x + i);
    float4 b = *(const float4*)(x + i + 4);
    u16x8 o;
    o[0] = f2b(a.x); o[1] = f2b(a.y); o[2] = f2b(a.z); o[3] = f2b(a.w);
    o[4] = f2b(b.x); o[5] = f2b(b.y); o[6] = f2b(b.z); o[7] = f2b(b.w);
    *(u16x8*)(xb + i) = o;
}

// ------- fused transpose+cast of all 3 weights: src [1024][N] f32 -> dst [N][1024] bf16 -------
// z=0: Wq (scale = 0.125*log2e folded for exp2-domain softmax), z=1: Wkv, z=2: Wo
__global__ __launch_bounds__(256)
void transpose_all(const float* __restrict__ Wq, const float* __restrict__ Wkv,
                   const float* __restrict__ Wo, u16* __restrict__ WcatT,
                   u16* __restrict__ WoT) {
    const int z = blockIdx.z;
    if (z != 1 && blockIdx.y >= 16) return;
    const float* src; u16* dst; int N; float scale;
    if (z == 0)      { src = Wq;  dst = WcatT;               N = 1024; scale = 0.125f * 1.44269504089f; }
    else if (z == 1) { src = Wkv; dst = WcatT + 1024 * 1024; N = 2048; scale = 1.0f; }
    else             { src = Wo;  dst = WoT;                 N = 1024; scale = 1.0f; }
    __shared__ __attribute__((aligned(16))) u16 tile[64][72];
    const int k0 = blockIdx.x * 64, n0 = blockIdx.y * 64;
    const int tid = threadIdx.x;
#pragma unroll
    for (int p = 0; p < 4; ++p) {
        int c = p * 256 + tid;
        int r = c >> 4, c4 = c & 15;
        float4 v = *(const float4*)(src + (size_t)(k0 + r) * N + n0 + c4 * 4);
        u16x4 o;
        o[0] = f2b(v.x * scale); o[1] = f2b(v.y * scale);
        o[2] = f2b(v.z * scale); o[3] = f2b(v.w * scale);
        *(u16x4*)&tile[r][c4 * 4] = o;
    }
    __syncthreads();
#pragma unroll
    for (int p = 0; p < 4; ++p) {
        int c = p * 256 + tid;
        int n = c >> 4, k4 = c & 15;
        u16x4 o;
#pragma unroll
        for (int i = 0; i < 4; ++i) o[i] = tile[k4 * 4 + i][n];
        *(u16x4*)(dst + (size_t)(n0 + n) * 1024 + k0 + k4 * 4) = o;
    }
}

// ------- GEMM: C[M,N] = A[M,K] @ B[K,N], B given transposed BT[N,K]. bf16 MFMA -------
// dbuf T3-minimum schedule (R2: neutral; kept). R6: XCD-chunked 1-D grid (kept).
// R7: V-FUSED EPILOGUE (kept; proven -6.5us). For n0 >= 2048 (V tiles) the tile
// is written DIRECTLY to VT[bh][hd][s'] sigma^-1-permuted, QKV C-write skipped.
// col = (sb&32)|((sb&12)<<1)|((sb>>2)&4), sb = s&63 (4-aligned).
// R10 NOTE: the 256^2 8-phase deep pipeline was tried and REGRESSED here —
// this shape gives only 192 blocks (<256 CUs, 1 block/CU at 128KB LDS) and
// K=1024 (8 pipeline iters): wrong regime for that template. Keep 128^2 2-phase.
template <typename OutT>
__global__ __launch_bounds__(256, 3)
void gemm_bt(const u16* __restrict__ A, const u16* __restrict__ BT,
             OutT* __restrict__ C, u16* __restrict__ VTg, int M, int N, int K) {
    __shared__ __attribute__((aligned(16))) u16 As[2][128 * 32];
    __shared__ __attribute__((aligned(16))) u16 Bs[2][128 * 32];
    const int tid = threadIdx.x;
    const int wave = tid >> 6, lane = tid & 63;
    const int l15 = lane & 15, quad = lane >> 4;
    // XCD-chunked decode: XCD k (wid%8) owns logical tiles [k*per, (k+1)*per)
    const int wid = blockIdx.x;
    const int per = (int)(gridDim.x >> 3);
    const int logical = (wid & 7) * per + (wid >> 3);
    const int nxt = N >> 7;
    const int ty = logical / nxt, tx = logical - ty * nxt;
    const int m0 = ty * 128, n0 = tx * 128;
    const int wm = (wave >> 1) * 64, wn = (wave & 1) * 64;
    const f32x4 zero = {0.f, 0.f, 0.f, 0.f};
    f32x4 acc[4][4];
#pragma unroll
    for (int i = 0; i < 4; ++i)
#pragma unroll
        for (int j = 0; j < 4; ++j) acc[i][j] = zero;
    const int r0 = tid >> 2, kc = (tid & 3) * 8;
    auto stage = [&](int bsel, int k0) {
        async_copy16(A + (size_t)(m0 + r0) * K + k0 + kc, As[bsel] + tid * 8);
        async_copy16(BT + (size_t)(n0 + r0) * K + k0 + kc, Bs[bsel] + tid * 8);
        async_copy16(A + (size_t)(m0 + 64 + r0) * K + k0 + kc, As[bsel] + (256 + tid) * 8);
        async_copy16(BT + (size_t)(n0 + 64 + r0) * K + k0 + kc, Bs[bsel] + (256 + tid) * 8);
    };
    stage(0, 0);
    __syncthreads();
    const int nk = K >> 5;
    for (int t = 0; t < nk; ++t) {
        if (t + 1 < nk) stage((t + 1) & 1, (t + 1) * 32);
        const u16* Ab = As[t & 1];
        const u16* Bb = Bs[t & 1];
        bf16x8 af[4], bf[4];
#pragma unroll
        for (int s = 0; s < 4; ++s) {
            af[s] = ldfrag(Ab + (wm + s * 16 + l15) * 32 + quad * 8);
            bf[s] = ldfrag(Bb + (wn + s * 16 + l15) * 32 + quad * 8);
        }
#pragma unroll
        for (int mt = 0; mt < 4; ++mt)
#pragma unroll
            for (int nt = 0; nt < 4; ++nt)
                acc[mt][nt] = __builtin_amdgcn_mfma_f32_16x16x32_bf16(
                    af[mt], bf[nt], acc[mt][nt], 0, 0, 0);
        __syncthreads();
    }
    if constexpr (sizeof(OutT) == 2) {
        if (n0 >= 2048) {
            // V tile -> VT[bh][hd][s'] directly (sigma^-1), skip QKV C-write.
#pragma unroll
            for (int mt = 0; mt < 4; ++mt)
#pragma unroll
                for (int nt = 0; nt < 4; ++nt) {
                    const int n_g = n0 + wn + nt * 16 + l15 - 2048;
                    const int hd = n_g & 63, h = n_g >> 6;
                    const int m_g = m0 + wm + mt * 16 + quad * 4;
                    const int bb = m_g >> 11;
                    const int s = m_g & 2047;
                    const int sb = s & 63;
                    const int col = (sb & 32) | ((sb & 12) << 1) | ((sb >> 2) & 4);
                    u16x4 o;
#pragma unroll
                    for (int r = 0; r < 4; ++r) o[r] = f2b(acc[mt][nt][r]);
                    *(u16x4*)(VTg + ((size_t)(bb * 16 + h) * 64 + hd) * 2048
                              + (s & ~63) + col) = o;
                }
            return;
        }
    }
#pragma unroll
    for (int mt = 0; mt < 4; ++mt)
#pragma unroll
        for (int nt = 0; nt < 4; ++nt) {
            const int n = n0 + wn + nt * 16 + l15;
#pragma unroll
            for (int r = 0; r < 4; ++r) {
                const int m = m0 + wm + mt * 16 + quad * 4 + r;
                float v = acc[mt][nt][r];
                if constexpr (sizeof(OutT) == 2) C[(size_t)m * N + n] = (OutT)f2b(v);
                else                             C[(size_t)m * N + n] = v;
            }
        }
}

// ------- GEMM variant: 128x64 tile (for N=1024 out-proj). dbuf + XCD chunking. -------
__global__ __launch_bounds__(256, 2)
void gemm_bt64(const u16* __restrict__ A, const u16* __restrict__ BT,
               float* __restrict__ C, int M, int N, int K) {
    __shared__ __attribute__((aligned(16))) u16 As[2][128 * 32];
    __shared__ __attribute__((aligned(16))) u16 Bs[2][64 * 32];
    const int tid = threadIdx.x;
    const int wave = tid >> 6, lane = tid & 63;
    const int l15 = lane & 15, quad = lane >> 4;
    const int wid = blockIdx.x;
    const int per = (int)(gridDim.x >> 3);
    const int logical = (wid & 7) * per + (wid >> 3);
    const int nxt = N >> 6;
    const int ty = logical / nxt, tx = logical - ty * nxt;
    const int m0 = ty * 128, n0 = tx * 64;
    const int wm = (wave >> 1) * 64, wn = (wave & 1) * 32;
    const f32x4 zero = {0.f, 0.f, 0.f, 0.f};
    f32x4 acc[4][2];
#pragma unroll
    for (int i = 0; i < 4; ++i)
#pragma unroll
        for (int j = 0; j < 2; ++j) acc[i][j] = zero;
    const int r0 = tid >> 2, kc = (tid & 3) * 8;
    auto stage = [&](int bsel, int k0) {
        async_copy16(A + (size_t)(m0 + r0) * K + k0 + kc, As[bsel] + tid * 8);
        async_copy16(A + (size_t)(m0 + 64 + r0) * K + k0 + kc, As[bsel] + (256 + tid) * 8);
        async_copy16(BT + (size_t)(n0 + r0) * K + k0 + kc, Bs[bsel] + tid * 8);
    };
    stage(0, 0);
    __syncthreads();
    const int nk = K >> 5;
    for (int t = 0; t < nk; ++t) {
        if (t + 1 < nk) stage((t + 1) & 1, (t + 1) * 32);
        const u16* Ab = As[t & 1];
        const u16* Bb = Bs[t & 1];
        bf16x8 af[4], bf[2];
#pragma unroll
        for (int s = 0; s < 4; ++s)
            af[s] = ldfrag(Ab + (wm + s * 16 + l15) * 32 + quad * 8);
#pragma unroll
        for (int s = 0; s < 2; ++s)
            bf[s] = ldfrag(Bb + (wn + s * 16 + l15) * 32 + quad * 8);
#pragma unroll
        for (int mt = 0; mt < 4; ++mt)
#pragma unroll
            for (int nt = 0; nt < 2; ++nt)
                acc[mt][nt] = __builtin_amdgcn_mfma_f32_16x16x32_bf16(
                    af[mt], bf[nt], acc[mt][nt], 0, 0, 0);
        __syncthreads();
    }
#pragma unroll
    for (int mt = 0; mt < 4; ++mt)
#pragma unroll
        for (int nt = 0; nt < 2; ++nt) {
            const int n = n0 + wn + nt * 16 + l15;
#pragma unroll
            for (int r = 0; r < 4; ++r) {
                const int m = m0 + wm + mt * 16 + quad * 4 + r;
                C[(size_t)m * N + n] = acc[mt][nt][r];
            }
        }
}

// ------- flash attention, causal, fixed-shift softmax, P-in-registers. -------
// R6 winner, UNCHANGED: dual-tile, KVBLK=64, XCD-chunked pair-balanced grid.
__global__ __launch_bounds__(256, 2)
void attn_kernel(const u16* __restrict__ QKV, const u16* __restrict__ VTg,
                 u16* __restrict__ AO) {
    __shared__ __attribute__((aligned(16))) u16 Kt[2][2 * 64 * 32];
    __shared__ __attribute__((aligned(16))) u16 Vt[2][2 * 64 * 32];
    const int tid = threadIdx.x;
    const int wave = tid >> 6, lane = tid & 63;
    const int l15 = lane & 15, quad = lane >> 4;
    const int w16 = wave * 16;
    // XCD-chunked, pair-balanced decode (512 blocks, 64 per XCD)
    const int wid = blockIdx.x;
    const int g = wid >> 3;                 // 0..63 slot within this XCD
    const int jj = g & 15, hf = jj >> 1;
    const int xe0 = (jj & 1) ? 15 - hf : hf;   // 0,15,1,14,...
    const int xe = (g & 32) ? 15 - xe0 : xe0;  // mirrored upper half
    const int bh = (wid & 7) * 4 + (g >> 4);   // 4 bh per XCD
    const int b = bh >> 4, h = bh & 15;
    const int qbA = 31 - xe, qbB = xe;
    const int qA0 = qbA * 64, qB0 = qbB * 64;
    const size_t bS = (size_t)b * SS;
    const u16* vbase = VTg + (size_t)bh * 64 * 2048;
    const int rr = (tid >> 2) & 63, kc8 = (tid & 3) * 8;

    // stage kv block 0
    {
        const u16* ksrc = QKV + (bS + rr) * 3072 + 1024 + h * 64 + kc8;
        async_copy16(ksrc,      Kt[0] + tid * 8);
        async_copy16(ksrc + 32, Kt[0] + (256 + tid) * 8);
        const u16* vsrc = vbase + (size_t)rr * 2048 + kc8;
        async_copy16(vsrc,      Vt[0] + tid * 8);
        async_copy16(vsrc + 32, Vt[0] + (256 + tid) * 8);
    }
    // Q direct global->reg: wave's own 16 q-rows per tile
    bf16x8 qfA[2], qfB[2];
    {
        const u16* qA = QKV + (bS + qA0 + w16 + l15) * 3072 + h * 64 + quad * 8;
        qfA[0] = ldfrag(qA); qfA[1] = ldfrag(qA + 32);
        const u16* qB = QKV + (bS + qB0 + w16 + l15) * 3072 + h * 64 + quad * 8;
        qfB[0] = ldfrag(qB); qfB[1] = ldfrag(qB + 32);
    }
    float lA = 0.f, lB = 0.f;
    f32x4 OA[4], OB[4];
    const f32x4 zero = {0.f, 0.f, 0.f, 0.f};
#pragma unroll
    for (int nt = 0; nt < 4; ++nt) { OA[nt] = zero; OB[nt] = zero; }
    const f32x4 cinit = {-10.f, -10.f, -10.f, -10.f};  // folded softmax shift
    __syncthreads();  // kv block 0 staged

    for (int j = 0; j <= qbA; ++j) {
        if (j < qbA) {  // prefetch j+1; drained by end-of-iter barrier (full cover)
            const int kv1 = (j + 1) * 64;
            const int nb = (j + 1) & 1;
            const u16* ksrc = QKV + (bS + kv1 + rr) * 3072 + 1024 + h * 64 + kc8;
            async_copy16(ksrc,      Kt[nb] + tid * 8);
            async_copy16(ksrc + 32, Kt[nb] + (256 + tid) * 8);
            const u16* vsrc = vbase + (size_t)rr * 2048 + kv1 + kc8;
            async_copy16(vsrc,      Vt[nb] + tid * 8);
            async_copy16(vsrc + 32, Vt[nb] + (256 + tid) * 8);
        }
        const bool bAct = (j <= qbB);  // block-uniform
        const bool dA = (j == qbA), dB = (j == qbB);
        const u16* KB = Kt[j & 1];
        const u16* VB = Vt[j & 1];
        bf16x8 vf[4][2];
#pragma unroll
        for (int nt = 0; nt < 4; ++nt)
#pragma unroll
            for (int ks = 0; ks < 2; ++ks)
                vf[nt][ks] = ldfrag(VB + ks * 2048 + (nt * 16 + l15) * 32 + quad * 8);
        // S^T over all 4 kv-subtiles for this wave's q-rows; P stays in regs.
        u16x4 pcA[4], pcB[4];
#pragma unroll
        for (int c = 0; c < 4; ++c) {
            bf16x8 kf0 = ldfrag(KB + (c * 16 + l15) * 32 + quad * 8);
            bf16x8 kf1 = ldfrag(KB + 2048 + (c * 16 + l15) * 32 + quad * 8);
            f32x4 a = __builtin_amdgcn_mfma_f32_16x16x32_bf16(kf0, qfA[0], cinit, 0, 0, 0);
            f32x4 s = __builtin_amdgcn_mfma_f32_16x16x32_bf16(kf1, qfA[1], a, 0, 0, 0);
            if (dA) {  // mask iff local kv > local q
#pragma unroll
                for (int r = 0; r < 4; ++r)
                    if (c * 16 + quad * 4 + r > w16 + l15) s[r] = -1e30f;
            }
            u16x4 pk; float acc = 0.f;
#pragma unroll
            for (int r = 0; r < 4; ++r) {
                float pv = fexp2(s[r]);
                acc += pv;
                pk[r] = f2b(pv);
            }
            lA += acc; pcA[c] = pk;
            if (bAct) {
                f32x4 a2 = __builtin_amdgcn_mfma_f32_16x16x32_bf16(kf0, qfB[0], cinit, 0, 0, 0);
                f32x4 s2 = __builtin_amdgcn_mfma_f32_16x16x32_bf16(kf1, qfB[1], a2, 0, 0, 0);
                if (dB) {
#pragma unroll
                    for (int r = 0; r < 4; ++r)
                        if (c * 16 + quad * 4 + r > w16 + l15) s2[r] = -1e30f;
                }
                u16x4 pk2; float acc2 = 0.f;
#pragma unroll
                for (int r = 0; r < 4; ++r) {
                    float pv = fexp2(s2[r]);
                    acc2 += pv;
                    pk2[r] = f2b(pv);
                }
                lB += acc2; pcB[c] = pk2;
            }
        }
        // PV: A-frag = own registers in (c,r) order, matching sigma-permuted V.
        bf16x8 paA[2], paB[2];
#pragma unroll
        for (int ks = 0; ks < 2; ++ks) {
            u16x8 t;
#pragma unroll
            for (int i = 0; i < 4; ++i) { t[i] = pcA[2 * ks][i]; t[4 + i] = pcA[2 * ks + 1][i]; }
            paA[ks] = __builtin_bit_cast(bf16x8, t);
        }
#pragma unroll
        for (int nt = 0; nt < 4; ++nt) {
            OA[nt] = __builtin_amdgcn_mfma_f32_16x16x32_bf16(paA[0], vf[nt][0], OA[nt], 0, 0, 0);
            OA[nt] = __builtin_amdgcn_mfma_f32_16x16x32_bf16(paA[1], vf[nt][1], OA[nt], 0, 0, 0);
        }
        if (bAct) {
#pragma unroll
            for (int ks = 0; ks < 2; ++ks) {
                u16x8 t;
#pragma unroll
                for (int i = 0; i < 4; ++i) { t[i] = pcB[2 * ks][i]; t[4 + i] = pcB[2 * ks + 1][i]; }
                paB[ks] = __builtin_bit_cast(bf16x8, t);
            }
#pragma unroll
            for (int nt = 0; nt < 4; ++nt) {
                OB[nt] = __builtin_amdgcn_mfma_f32_16x16x32_bf16(paB[0], vf[nt][0], OB[nt], 0, 0, 0);
                OB[nt] = __builtin_amdgcn_mfma_f32_16x16x32_bf16(paB[1], vf[nt][1], OB[nt], 0, 0, 0);
            }
        }
        __syncthreads();  // reads done + prefetch j+1 landed
    }

    // epilogue: all-shuffle. l partial per lane; xor16+xor32 sums the quads.
    lA += __shfl_xor(lA, 16); lA += __shfl_xor(lA, 32);
    lB += __shfl_xor(lB, 16); lB += __shfl_xor(lB, 32);
#pragma unroll
    for (int r = 0; r < 4; ++r) {
        const int ql = quad * 4 + r;   // local q row of O (D layout: row=quad*4+r)
        float invA = 1.0f / __shfl(lA, ql);
        float invB = 1.0f / __shfl(lB, ql);
        size_t rowA = bS + (size_t)qA0 + w16 + ql;
        size_t rowB = bS + (size_t)qB0 + w16 + ql;
#pragma unroll
        for (int nt = 0; nt < 4; ++nt) {
            AO[rowA * 1024 + h * 64 + nt * 16 + l15] = f2b(OA[nt][r] * invA);
            AO[rowB * 1024 + h * 64 + nt * 16 + l15] = f2b(OB[nt][r] * invB);
        }
    }
}

extern "C" void kernel_launch(void* const* d_in, const int* in_sizes, int n_in,
                              void* d_out, int out_size, void* d_ws, size_t ws_size,
                              hipStream_t stream) {
    (void)in_sizes; (void)n_in; (void)out_size; (void)ws_size;
    const float* x   = (const float*)d_in[0];
    const float* Wq  = (const float*)d_in[1];
    const float* Wkv = (const float*)d_in[2];
    const float* Wo  = (const float*)d_in[3];
    float* out = (float*)d_out;
    char* ws = (char*)d_ws;
    u16* xb    = (u16*)(ws);                      // 8 MB   x bf16 [4096][1024]
    u16* WcatT = (u16*)(ws + (size_t)(8 << 20));  // 6 MB   [Wq*s | Wkv]^T  [3072][1024]
    u16* WoT   = (u16*)(ws + (size_t)(14 << 20)); // 2 MB   Wo^T [1024][1024]
    u16* QKV   = (u16*)(ws + (size_t)(16 << 20)); // 24 MB  [4096][3072] (V cols unused)
    u16* VTb   = (u16*)(ws + (size_t)(40 << 20)); // 8 MB   [32][64][2048] sigma-permuted
    u16* AO    = xb;                              // reuse: xb dead after QKV GEMM

    cast_x_kernel<<<2048, 256, 0, stream>>>(x, xb);
    transpose_all<<<dim3(16, 32, 3), 256, 0, stream>>>(Wq, Wkv, Wo, WcatT, WoT);
    gemm_bt<u16><<<768, 256, 0, stream>>>(xb, WcatT, QKV, VTb, 4096, 3072, 1024);
    attn_kernel<<<512, 256, 0, stream>>>(QKV, VTb, AO);
    gemm_bt64<<<512, 256, 0, stream>>>(AO, WoT, out, 4096, 1024, 1024);
}

// Round 13
// 168.879 us; speedup vs baseline: 1.0647x; 1.0223x over previous
//
#include <hip/hip_runtime.h>

typedef __bf16 bf16_t;
typedef unsigned short u16;
typedef __attribute__((ext_vector_type(8))) __bf16 bf16x8;
typedef __attribute__((ext_vector_type(4))) float f32x4;
typedef __attribute__((ext_vector_type(4))) u16 u16x4;
typedef __attribute__((ext_vector_type(8))) u16 u16x8;

#define SS 2048

__device__ __forceinline__ u16 f2b(float f) {
    return __builtin_bit_cast(u16, (__bf16)f);
}

// exp2 in ONE VALU op (v_exp_f32).
__device__ __forceinline__ float fexp2(float x) {
#if __has_builtin(__builtin_amdgcn_exp2f)
    return __builtin_amdgcn_exp2f(x);
#else
    float r;
    asm("v_exp_f32 %0, %1" : "=v"(r) : "v"(x));
    return r;
#endif
}

__device__ __forceinline__ void async_copy16(const u16* g, u16* l) {
    __builtin_amdgcn_global_load_lds(
        (__attribute__((address_space(1))) void*)(u16*)g,
        (__attribute__((address_space(3))) void*)l, 16, 0, 0);
}

__device__ __forceinline__ bf16x8 ldfrag(const u16* p) {
    return __builtin_bit_cast(bf16x8, *(const u16x8*)p);
}

// ------- R12/R13: MERGED prologue: weight transposes + x cast in ONE dispatch -------
// z=0: Wq^T (scale = 0.125*log2e folded for exp2-domain softmax), z=1: Wkv^T,
// z=2: Wo^T, z=3: x f32->bf16 cast (512 blocks, 4 chunks each).
// cast_x and transpose_all are independent (x vs weights) but were serialized
// as two launches; merged they overlap as one 48MB memory-bound dispatch and
// one launch gap is deleted. Numerics bit-identical (same f2b on same values).
// (R12 bench was an infra failure — resubmitted unchanged.)
__global__ __launch_bounds__(256)
void prep_all(const float* __restrict__ x, const float* __restrict__ Wq,
              const float* __restrict__ Wkv, const float* __restrict__ Wo,
              u16* __restrict__ xb, u16* __restrict__ WcatT,
              u16* __restrict__ WoT) {
    const int z = blockIdx.z;
    const int tid = threadIdx.x;
    if (z == 3) {  // x cast: 512 blocks x 4 chunks = 2048 chunks of 2048 elems
        const int id = blockIdx.y * 16 + blockIdx.x;
#pragma unroll
        for (int c = 0; c < 4; ++c) {
            size_t i = ((size_t)(id * 4 + c) * 256 + tid) * 8;
            float4 a = *(const float4*)(x + i);
            float4 b = *(const float4*)(x + i + 4);
            u16x8 o;
            o[0] = f2b(a.x); o[1] = f2b(a.y); o[2] = f2b(a.z); o[3] = f2b(a.w);
            o[4] = f2b(b.x); o[5] = f2b(b.y); o[6] = f2b(b.z); o[7] = f2b(b.w);
            *(u16x8*)(xb + i) = o;
        }
        return;
    }
    if (z != 1 && blockIdx.y >= 16) return;
    const float* src; u16* dst; int N; float scale;
    if (z == 0)      { src = Wq;  dst = WcatT;               N = 1024; scale = 0.125f * 1.44269504089f; }
    else if (z == 1) { src = Wkv; dst = WcatT + 1024 * 1024; N = 2048; scale = 1.0f; }
    else             { src = Wo;  dst = WoT;                 N = 1024; scale = 1.0f; }
    __shared__ __attribute__((aligned(16))) u16 tile[64][72];
    const int k0 = blockIdx.x * 64, n0 = blockIdx.y * 64;
#pragma unroll
    for (int p = 0; p < 4; ++p) {
        int c = p * 256 + tid;
        int r = c >> 4, c4 = c & 15;
        float4 v = *(const float4*)(src + (size_t)(k0 + r) * N + n0 + c4 * 4);
        u16x4 o;
        o[0] = f2b(v.x * scale); o[1] = f2b(v.y * scale);
        o[2] = f2b(v.z * scale); o[3] = f2b(v.w * scale);
        *(u16x4*)&tile[r][c4 * 4] = o;
    }
    __syncthreads();
#pragma unroll
    for (int p = 0; p < 4; ++p) {
        int c = p * 256 + tid;
        int n = c >> 4, k4 = c & 15;
        u16x4 o;
#pragma unroll
        for (int i = 0; i < 4; ++i) o[i] = tile[k4 * 4 + i][n];
        *(u16x4*)(dst + (size_t)(n0 + n) * 1024 + k0 + k4 * 4) = o;
    }
}

// ------- GEMM: C[M,N] = A[M,K] @ B[K,N], B given transposed BT[N,K]. bf16 MFMA -------
// dbuf T3-minimum schedule (R2: neutral; kept). R6: XCD-chunked 1-D grid (kept).
// R7: V-FUSED EPILOGUE (kept; proven -6.5us). For n0 >= 2048 (V tiles) the tile
// is written DIRECTLY to VT[bh][hd][s'] sigma^-1-permuted, QKV C-write skipped.
// col = (sb&32)|((sb&12)<<1)|((sb>>2)&4), sb = s&63 (4-aligned).
// R10 NOTE: the 256^2 8-phase deep pipeline was tried and REGRESSED here —
// this shape gives only 192 blocks (<256 CUs, 1 block/CU at 128KB LDS) and
// K=1024 (8 pipeline iters): wrong regime for that template. Keep 128^2 2-phase.
// R8 NOTE: fusing the x-cast into A-staging also REGRESSED (critical-path cvt).
template <typename OutT>
__global__ __launch_bounds__(256, 3)
void gemm_bt(const u16* __restrict__ A, const u16* __restrict__ BT,
             OutT* __restrict__ C, u16* __restrict__ VTg, int M, int N, int K) {
    __shared__ __attribute__((aligned(16))) u16 As[2][128 * 32];
    __shared__ __attribute__((aligned(16))) u16 Bs[2][128 * 32];
    const int tid = threadIdx.x;
    const int wave = tid >> 6, lane = tid & 63;
    const int l15 = lane & 15, quad = lane >> 4;
    // XCD-chunked decode: XCD k (wid%8) owns logical tiles [k*per, (k+1)*per)
    const int wid = blockIdx.x;
    const int per = (int)(gridDim.x >> 3);
    const int logical = (wid & 7) * per + (wid >> 3);
    const int nxt = N >> 7;
    const int ty = logical / nxt, tx = logical - ty * nxt;
    const int m0 = ty * 128, n0 = tx * 128;
    const int wm = (wave >> 1) * 64, wn = (wave & 1) * 64;
    const f32x4 zero = {0.f, 0.f, 0.f, 0.f};
    f32x4 acc[4][4];
#pragma unroll
    for (int i = 0; i < 4; ++i)
#pragma unroll
        for (int j = 0; j < 4; ++j) acc[i][j] = zero;
    const int r0 = tid >> 2, kc = (tid & 3) * 8;
    auto stage = [&](int bsel, int k0) {
        async_copy16(A + (size_t)(m0 + r0) * K + k0 + kc, As[bsel] + tid * 8);
        async_copy16(BT + (size_t)(n0 + r0) * K + k0 + kc, Bs[bsel] + tid * 8);
        async_copy16(A + (size_t)(m0 + 64 + r0) * K + k0 + kc, As[bsel] + (256 + tid) * 8);
        async_copy16(BT + (size_t)(n0 + 64 + r0) * K + k0 + kc, Bs[bsel] + (256 + tid) * 8);
    };
    stage(0, 0);
    __syncthreads();
    const int nk = K >> 5;
    for (int t = 0; t < nk; ++t) {
        if (t + 1 < nk) stage((t + 1) & 1, (t + 1) * 32);
        const u16* Ab = As[t & 1];
        const u16* Bb = Bs[t & 1];
        bf16x8 af[4], bf[4];
#pragma unroll
        for (int s = 0; s < 4; ++s) {
            af[s] = ldfrag(Ab + (wm + s * 16 + l15) * 32 + quad * 8);
            bf[s] = ldfrag(Bb + (wn + s * 16 + l15) * 32 + quad * 8);
        }
#pragma unroll
        for (int mt = 0; mt < 4; ++mt)
#pragma unroll
            for (int nt = 0; nt < 4; ++nt)
                acc[mt][nt] = __builtin_amdgcn_mfma_f32_16x16x32_bf16(
                    af[mt], bf[nt], acc[mt][nt], 0, 0, 0);
        __syncthreads();
    }
    if constexpr (sizeof(OutT) == 2) {
        if (n0 >= 2048) {
            // V tile -> VT[bh][hd][s'] directly (sigma^-1), skip QKV C-write.
#pragma unroll
            for (int mt = 0; mt < 4; ++mt)
#pragma unroll
                for (int nt = 0; nt < 4; ++nt) {
                    const int n_g = n0 + wn + nt * 16 + l15 - 2048;
                    const int hd = n_g & 63, h = n_g >> 6;
                    const int m_g = m0 + wm + mt * 16 + quad * 4;
                    const int bb = m_g >> 11;
                    const int s = m_g & 2047;
                    const int sb = s & 63;
                    const int col = (sb & 32) | ((sb & 12) << 1) | ((sb >> 2) & 4);
                    u16x4 o;
#pragma unroll
                    for (int r = 0; r < 4; ++r) o[r] = f2b(acc[mt][nt][r]);
                    *(u16x4*)(VTg + ((size_t)(bb * 16 + h) * 64 + hd) * 2048
                              + (s & ~63) + col) = o;
                }
            return;
        }
    }
#pragma unroll
    for (int mt = 0; mt < 4; ++mt)
#pragma unroll
        for (int nt = 0; nt < 4; ++nt) {
            const int n = n0 + wn + nt * 16 + l15;
#pragma unroll
            for (int r = 0; r < 4; ++r) {
                const int m = m0 + wm + mt * 16 + quad * 4 + r;
                float v = acc[mt][nt][r];
                if constexpr (sizeof(OutT) == 2) C[(size_t)m * N + n] = (OutT)f2b(v);
                else                             C[(size_t)m * N + n] = v;
            }
        }
}

// ------- GEMM variant: 128x64 tile (for N=1024 out-proj). dbuf + XCD chunking. -------
__global__ __launch_bounds__(256, 2)
void gemm_bt64(const u16* __restrict__ A, const u16* __restrict__ BT,
               float* __restrict__ C, int M, int N, int K) {
    __shared__ __attribute__((aligned(16))) u16 As[2][128 * 32];
    __shared__ __attribute__((aligned(16))) u16 Bs[2][64 * 32];
    const int tid = threadIdx.x;
    const int wave = tid >> 6, lane = tid & 63;
    const int l15 = lane & 15, quad = lane >> 4;
    const int wid = blockIdx.x;
    const int per = (int)(gridDim.x >> 3);
    const int logical = (wid & 7) * per + (wid >> 3);
    const int nxt = N >> 6;
    const int ty = logical / nxt, tx = logical - ty * nxt;
    const int m0 = ty * 128, n0 = tx * 64;
    const int wm = (wave >> 1) * 64, wn = (wave & 1) * 32;
    const f32x4 zero = {0.f, 0.f, 0.f, 0.f};
    f32x4 acc[4][2];
#pragma unroll
    for (int i = 0; i < 4; ++i)
#pragma unroll
        for (int j = 0; j < 2; ++j) acc[i][j] = zero;
    const int r0 = tid >> 2, kc = (tid & 3) * 8;
    auto stage = [&](int bsel, int k0) {
        async_copy16(A + (size_t)(m0 + r0) * K + k0 + kc, As[bsel] + tid * 8);
        async_copy16(A + (size_t)(m0 + 64 + r0) * K + k0 + kc, As[bsel] + (256 + tid) * 8);
        async_copy16(BT + (size_t)(n0 + r0) * K + k0 + kc, Bs[bsel] + tid * 8);
    };
    stage(0, 0);
    __syncthreads();
    const int nk = K >> 5;
    for (int t = 0; t < nk; ++t) {
        if (t + 1 < nk) stage((t + 1) & 1, (t + 1) * 32);
        const u16* Ab = As[t & 1];
        const u16* Bb = Bs[t & 1];
        bf16x8 af[4], bf[2];
#pragma unroll
        for (int s = 0; s < 4; ++s)
            af[s] = ldfrag(Ab + (wm + s * 16 + l15) * 32 + quad * 8);
#pragma unroll
        for (int s = 0; s < 2; ++s)
            bf[s] = ldfrag(Bb + (wn + s * 16 + l15) * 32 + quad * 8);
#pragma unroll
        for (int mt = 0; mt < 4; ++mt)
#pragma unroll
            for (int nt = 0; nt < 2; ++nt)
                acc[mt][nt] = __builtin_amdgcn_mfma_f32_16x16x32_bf16(
                    af[mt], bf[nt], acc[mt][nt], 0, 0, 0);
        __syncthreads();
    }
#pragma unroll
    for (int mt = 0; mt < 4; ++mt)
#pragma unroll
        for (int nt = 0; nt < 2; ++nt) {
            const int n = n0 + wn + nt * 16 + l15;
#pragma unroll
            for (int r = 0; r < 4; ++r) {
                const int m = m0 + wm + mt * 16 + quad * 4 + r;
                C[(size_t)m * N + n] = acc[mt][nt][r];
            }
        }
}

// ------- flash attention, causal, fixed-shift softmax, P-in-registers. -------
// R6 winner, UNCHANGED: dual-tile, KVBLK=64, XCD-chunked pair-balanced grid.
__global__ __launch_bounds__(256, 2)
void attn_kernel(const u16* __restrict__ QKV, const u16* __restrict__ VTg,
                 u16* __restrict__ AO) {
    __shared__ __attribute__((aligned(16))) u16 Kt[2][2 * 64 * 32];
    __shared__ __attribute__((aligned(16))) u16 Vt[2][2 * 64 * 32];
    const int tid = threadIdx.x;
    const int wave = tid >> 6, lane = tid & 63;
    const int l15 = lane & 15, quad = lane >> 4;
    const int w16 = wave * 16;
    // XCD-chunked, pair-balanced decode (512 blocks, 64 per XCD)
    const int wid = blockIdx.x;
    const int g = wid >> 3;                 // 0..63 slot within this XCD
    const int jj = g & 15, hf = jj >> 1;
    const int xe0 = (jj & 1) ? 15 - hf : hf;   // 0,15,1,14,...
    const int xe = (g & 32) ? 15 - xe0 : xe0;  // mirrored upper half
    const int bh = (wid & 7) * 4 + (g >> 4);   // 4 bh per XCD
    const int b = bh >> 4, h = bh & 15;
    const int qbA = 31 - xe, qbB = xe;
    const int qA0 = qbA * 64, qB0 = qbB * 64;
    const size_t bS = (size_t)b * SS;
    const u16* vbase = VTg + (size_t)bh * 64 * 2048;
    const int rr = (tid >> 2) & 63, kc8 = (tid & 3) * 8;

    // stage kv block 0
    {
        const u16* ksrc = QKV + (bS + rr) * 3072 + 1024 + h * 64 + kc8;
        async_copy16(ksrc,      Kt[0] + tid * 8);
        async_copy16(ksrc + 32, Kt[0] + (256 + tid) * 8);
        const u16* vsrc = vbase + (size_t)rr * 2048 + kc8;
        async_copy16(vsrc,      Vt[0] + tid * 8);
        async_copy16(vsrc + 32, Vt[0] + (256 + tid) * 8);
    }
    // Q direct global->reg: wave's own 16 q-rows per tile
    bf16x8 qfA[2], qfB[2];
    {
        const u16* qA = QKV + (bS + qA0 + w16 + l15) * 3072 + h * 64 + quad * 8;
        qfA[0] = ldfrag(qA); qfA[1] = ldfrag(qA + 32);
        const u16* qB = QKV + (bS + qB0 + w16 + l15) * 3072 + h * 64 + quad * 8;
        qfB[0] = ldfrag(qB); qfB[1] = ldfrag(qB + 32);
    }
    float lA = 0.f, lB = 0.f;
    f32x4 OA[4], OB[4];
    const f32x4 zero = {0.f, 0.f, 0.f, 0.f};
#pragma unroll
    for (int nt = 0; nt < 4; ++nt) { OA[nt] = zero; OB[nt] = zero; }
    const f32x4 cinit = {-10.f, -10.f, -10.f, -10.f};  // folded softmax shift
    __syncthreads();  // kv block 0 staged

    for (int j = 0; j <= qbA; ++j) {
        if (j < qbA) {  // prefetch j+1; drained by end-of-iter barrier (full cover)
            const int kv1 = (j + 1) * 64;
            const int nb = (j + 1) & 1;
            const u16* ksrc = QKV + (bS + kv1 + rr) * 3072 + 1024 + h * 64 + kc8;
            async_copy16(ksrc,      Kt[nb] + tid * 8);
            async_copy16(ksrc + 32, Kt[nb] + (256 + tid) * 8);
            const u16* vsrc = vbase + (size_t)rr * 2048 + kv1 + kc8;
            async_copy16(vsrc,      Vt[nb] + tid * 8);
            async_copy16(vsrc + 32, Vt[nb] + (256 + tid) * 8);
        }
        const bool bAct = (j <= qbB);  // block-uniform
        const bool dA = (j == qbA), dB = (j == qbB);
        const u16* KB = Kt[j & 1];
        const u16* VB = Vt[j & 1];
        bf16x8 vf[4][2];
#pragma unroll
        for (int nt = 0; nt < 4; ++nt)
#pragma unroll
            for (int ks = 0; ks < 2; ++ks)
                vf[nt][ks] = ldfrag(VB + ks * 2048 + (nt * 16 + l15) * 32 + quad * 8);
        // S^T over all 4 kv-subtiles for this wave's q-rows; P stays in regs.
        u16x4 pcA[4], pcB[4];
#pragma unroll
        for (int c = 0; c < 4; ++c) {
            bf16x8 kf0 = ldfrag(KB + (c * 16 + l15) * 32 + quad * 8);
            bf16x8 kf1 = ldfrag(KB + 2048 + (c * 16 + l15) * 32 + quad * 8);
            f32x4 a = __builtin_amdgcn_mfma_f32_16x16x32_bf16(kf0, qfA[0], cinit, 0, 0, 0);
            f32x4 s = __builtin_amdgcn_mfma_f32_16x16x32_bf16(kf1, qfA[1], a, 0, 0, 0);
            if (dA) {  // mask iff local kv > local q
#pragma unroll
                for (int r = 0; r < 4; ++r)
                    if (c * 16 + quad * 4 + r > w16 + l15) s[r] = -1e30f;
            }
            u16x4 pk; float acc = 0.f;
#pragma unroll
            for (int r = 0; r < 4; ++r) {
                float pv = fexp2(s[r]);
                acc += pv;
                pk[r] = f2b(pv);
            }
            lA += acc; pcA[c] = pk;
            if (bAct) {
                f32x4 a2 = __builtin_amdgcn_mfma_f32_16x16x32_bf16(kf0, qfB[0], cinit, 0, 0, 0);
                f32x4 s2 = __builtin_amdgcn_mfma_f32_16x16x32_bf16(kf1, qfB[1], a2, 0, 0, 0);
                if (dB) {
#pragma unroll
                    for (int r = 0; r < 4; ++r)
                        if (c * 16 + quad * 4 + r > w16 + l15) s2[r] = -1e30f;
                }
                u16x4 pk2; float acc2 = 0.f;
#pragma unroll
                for (int r = 0; r < 4; ++r) {
                    float pv = fexp2(s2[r]);
                    acc2 += pv;
                    pk2[r] = f2b(pv);
                }
                lB += acc2; pcB[c] = pk2;
            }
        }
        // PV: A-frag = own registers in (c,r) order, matching sigma-permuted V.
        bf16x8 paA[2], paB[2];
#pragma unroll
        for (int ks = 0; ks < 2; ++ks) {
            u16x8 t;
#pragma unroll
            for (int i = 0; i < 4; ++i) { t[i] = pcA[2 * ks][i]; t[4 + i] = pcA[2 * ks + 1][i]; }
            paA[ks] = __builtin_bit_cast(bf16x8, t);
        }
#pragma unroll
        for (int nt = 0; nt < 4; ++nt) {
            OA[nt] = __builtin_amdgcn_mfma_f32_16x16x32_bf16(paA[0], vf[nt][0], OA[nt], 0, 0, 0);
            OA[nt] = __builtin_amdgcn_mfma_f32_16x16x32_bf16(paA[1], vf[nt][1], OA[nt], 0, 0, 0);
        }
        if (bAct) {
#pragma unroll
            for (int ks = 0; ks < 2; ++ks) {
                u16x8 t;
#pragma unroll
                for (int i = 0; i < 4; ++i) { t[i] = pcB[2 * ks][i]; t[4 + i] = pcB[2 * ks + 1][i]; }
                paB[ks] = __builtin_bit_cast(bf16x8, t);
            }
#pragma unroll
            for (int nt = 0; nt < 4; ++nt) {
                OB[nt] = __builtin_amdgcn_mfma_f32_16x16x32_bf16(paB[0], vf[nt][0], OB[nt], 0, 0, 0);
                OB[nt] = __builtin_amdgcn_mfma_f32_16x16x32_bf16(paB[1], vf[nt][1], OB[nt], 0, 0, 0);
            }
        }
        __syncthreads();  // reads done + prefetch j+1 landed
    }

    // epilogue: all-shuffle. l partial per lane; xor16+xor32 sums the quads.
    lA += __shfl_xor(lA, 16); lA += __shfl_xor(lA, 32);
    lB += __shfl_xor(lB, 16); lB += __shfl_xor(lB, 32);
#pragma unroll
    for (int r = 0; r < 4; ++r) {
        const int ql = quad * 4 + r;   // local q row of O (D layout: row=quad*4+r)
        float invA = 1.0f / __shfl(lA, ql);
        float invB = 1.0f / __shfl(lB, ql);
        size_t rowA = bS + (size_t)qA0 + w16 + ql;
        size_t rowB = bS + (size_t)qB0 + w16 + ql;
#pragma unroll
        for (int nt = 0; nt < 4; ++nt) {
            AO[rowA * 1024 + h * 64 + nt * 16 + l15] = f2b(OA[nt][r] * invA);
            AO[rowB * 1024 + h * 64 + nt * 16 + l15] = f2b(OB[nt][r] * invB);
        }
    }
}

extern "C" void kernel_launch(void* const* d_in, const int* in_sizes, int n_in,
                              void* d_out, int out_size, void* d_ws, size_t ws_size,
                              hipStream_t stream) {
    (void)in_sizes; (void)n_in; (void)out_size; (void)ws_size;
    const float* x   = (const float*)d_in[0];
    const float* Wq  = (const float*)d_in[1];
    const float* Wkv = (const float*)d_in[2];
    const float* Wo  = (const float*)d_in[3];
    float* out = (float*)d_out;
    char* ws = (char*)d_ws;
    u16* xb    = (u16*)(ws);                      // 8 MB   x bf16 [4096][1024]
    u16* WcatT = (u16*)(ws + (size_t)(8 << 20));  // 6 MB   [Wq*s | Wkv]^T  [3072][1024]
    u16* WoT   = (u16*)(ws + (size_t)(14 << 20)); // 2 MB   Wo^T [1024][1024]
    u16* QKV   = (u16*)(ws + (size_t)(16 << 20)); // 24 MB  [4096][3072] (V cols unused)
    u16* VTb   = (u16*)(ws + (size_t)(40 << 20)); // 8 MB   [32][64][2048] sigma-permuted
    u16* AO    = xb;                              // reuse: xb dead after QKV GEMM

    prep_all<<<dim3(16, 32, 4), 256, 0, stream>>>(x, Wq, Wkv, Wo, xb, WcatT, WoT);
    gemm_bt<u16><<<768, 256, 0, stream>>>(xb, WcatT, QKV, VTb, 4096, 3072, 1024);
    attn_kernel<<<512, 256, 0, stream>>>(QKV, VTb, AO);
    gemm_bt64<<<512, 256, 0, stream>>>(AO, WoT, out, 4096, 1024, 1024);
}